// Round 1
// baseline (495.458 us; speedup 1.0000x reference)
//
#include <hip/hip_runtime.h>
#include <cstdint>
#include <cstddef>

#define BSZ    32
#define SEQL   2048
#define ENCD   512
#define DE     1024   // DEC + ENC
#define NHEADS 8
#define IHD    1024   // INTERM * HEADS

typedef unsigned short u16;
typedef __bf16 bf16x8 __attribute__((ext_vector_type(8)));
typedef float floatx4 __attribute__((ext_vector_type(4)));
typedef unsigned short u16x8 __attribute__((ext_vector_type(8)));

__device__ __forceinline__ u16 f2bf(float f) {
    unsigned int u = __float_as_uint(f);
    u = (u + 0x7FFFu + ((u >> 16) & 1u)) >> 16;   // RNE
    return (u16)u;
}
__device__ __forceinline__ float bf2f(u16 v) {
    return __uint_as_float(((unsigned int)v) << 16);
}
__device__ __forceinline__ float softplus_f(float x) {
    return fmaxf(x, 0.0f) + log1pf(__expf(-fabsf(x)));
}
__device__ __forceinline__ float tanh_fast(float x) {
    const float e = __expf(2.0f * x);
    return 1.0f - 2.0f / (e + 1.0f);
}
__device__ __forceinline__ void async_cp16(u16* lds, const u16* g) {
    __builtin_amdgcn_global_load_lds(
        (const __attribute__((address_space(1))) unsigned int*)g,
        (__attribute__((address_space(3))) unsigned int*)lds, 16, 0, 0);
}

// ---------------------------------------------------------------------------
// fp32 -> bf16 enc conversion (feeds gemm and context kernels)
// ---------------------------------------------------------------------------
__global__ __launch_bounds__(256) void conv_enc_kernel(const float* __restrict__ in,
                                                       u16* __restrict__ out) {
    const size_t i = (size_t)blockIdx.x * 256 + threadIdx.x;   // group of 8
    const float4* p = (const float4*)in + i * 2;
    const float4 a = p[0], b = p[1];
    u16x8 o;
    o[0] = f2bf(a.x); o[1] = f2bf(a.y); o[2] = f2bf(a.z); o[3] = f2bf(a.w);
    o[4] = f2bf(b.x); o[5] = f2bf(b.y); o[6] = f2bf(b.z); o[7] = f2bf(b.w);
    *((u16x8*)out + i) = o;
}

// ---------------------------------------------------------------------------
// bid<128: WvT[n][k] = bf16(Wv[k][n]) 64x64 LDS tile transpose
// bid==128: Wf -> bf16 (8192 elems + 8 pad zeros)
// ---------------------------------------------------------------------------
__global__ __launch_bounds__(256) void conv_w_kernel(const float* __restrict__ Wv,
                                                     const float* __restrict__ Wf,
                                                     u16* __restrict__ WvT,
                                                     u16* __restrict__ wfb) {
    __shared__ float tile[64 * 65];
    const int bid = blockIdx.x, tid = threadIdx.x;
    if (bid == 128) {
        for (int i = tid; i < 8200; i += 256)
            wfb[i] = (i < 8192) ? f2bf(Wf[i]) : (u16)0;
        return;
    }
    const int nt = bid & 15, kt = bid >> 4;
    for (int i = tid; i < 4096; i += 256) {
        const int kk = i >> 6, nn = i & 63;
        tile[kk * 65 + nn] = Wv[(size_t)(kt * 64 + kk) * IHD + nt * 64 + nn];
    }
    __syncthreads();
    for (int i = tid; i < 4096; i += 256) {
        const int nn = i >> 6, kk = i & 63;
        WvT[(size_t)(nt * 64 + nn) * 512 + kt * 64 + kk] = f2bf(tile[kk * 65 + nn]);
    }
}

// ---------------------------------------------------------------------------
// prep: grid (BSZ, 33). y<32: 32 query cols, 8-way k-split + LDS reduce.
//       y==32: beta = sp(dec@Wb+bb); kappa += sp(dec@Wk+bk)
// ---------------------------------------------------------------------------
__global__ __launch_bounds__(256) void prep_kernel(
    const float* __restrict__ dec, const float* __restrict__ kappa_in,
    const float* __restrict__ Wq, const float* __restrict__ bq,
    const float* __restrict__ Wb, const float* __restrict__ bb,
    const float* __restrict__ Wk, const float* __restrict__ bk,
    float* __restrict__ query_ws, float* __restrict__ beta_ws,
    float* __restrict__ kappa_out)
{
    __shared__ float s_dec[DE];
    __shared__ float s_red[256];
    const int b = blockIdx.x, y = blockIdx.y, tid = threadIdx.x;
    for (int i = tid; i < DE; i += 256) s_dec[i] = dec[b * DE + i];
    __syncthreads();

    if (y < 32) {
        const int cl = tid & 31, kg = tid >> 5;
        const int col = y * 32 + cl;
        float a = 0.f;
        const float* w = Wq + col;
        #pragma unroll 4
        for (int k = kg * 128; k < kg * 128 + 128; ++k)
            a = fmaf(s_dec[k], w[(size_t)k * IHD], a);
        s_red[tid] = a;
        __syncthreads();
        if (tid < 32) {
            float s = 0.f;
            #pragma unroll
            for (int i = 0; i < 8; ++i) s += s_red[i * 32 + tid];
            query_ws[(size_t)b * IHD + col] = s + bq[col];
        }
    } else {
        const int h = tid & 7, kg = tid >> 3;   // 32 k-groups of 32
        float ab = 0.f, ak = 0.f;
        for (int k = kg * 32; k < kg * 32 + 32; ++k) {
            const float d = s_dec[k];
            ab = fmaf(d, Wb[k * NHEADS + h], ab);
            ak = fmaf(d, Wk[k * NHEADS + h], ak);
        }
        s_red[tid] = ab;
        __syncthreads();
        for (int off = 128; off >= 8; off >>= 1) {
            if (tid < off) s_red[tid] += s_red[tid + off];
            __syncthreads();
        }
        const float abT = (tid < 8) ? s_red[tid] : 0.f;
        __syncthreads();
        s_red[tid] = ak;
        __syncthreads();
        for (int off = 128; off >= 8; off >>= 1) {
            if (tid < off) s_red[tid] += s_red[tid + off];
            __syncthreads();
        }
        if (tid < 8) {
            beta_ws[b * NHEADS + tid]   = softplus_f(bb[tid] + abT);
            kappa_out[b * NHEADS + tid] = kappa_in[b * NHEADS + tid]
                                        + softplus_f(bk[tid] + s_red[tid]);
        }
    }
}

// ---------------------------------------------------------------------------
// Main fused kernel. BM=128 -> 512 blocks (2 blocks/CU), LDS 64 KB.
// Double-buffered 2-phase K-loop: stage tile k+1 (global_load_lds) BEFORE
// computing tile k, so the barrier's vmcnt(0) drain lands after ~350cy of
// ds_read+MFMA instead of immediately after issue. 128 wave-MFMA per barrier
// pair (m97 geometry). tT (128x128 bf16, XOR-swizzled stride-128) aliases the
// just-consumed LDS buffer.
// ---------------------------------------------------------------------------
#define BM 128
#define BN 128
#define BK 64

__global__ __launch_bounds__(256, 2) void gemm_score_kernel(
    const u16* __restrict__ encb, const u16* __restrict__ wvT,
    const float* __restrict__ bv, const u16* __restrict__ wfb,
    const float* __restrict__ bf_g, const float* __restrict__ mask,
    const float* __restrict__ query_ws, const float* __restrict__ beta_ws,
    const float* __restrict__ kappa_out, float* __restrict__ score_out)
{
    // smem: buf0 [A 16KB | B 16KB] | buf1 [A 16KB | B 16KB]  = 64 KB
    __shared__ __align__(16) unsigned char smem[65536];

    const int tid  = threadIdx.x;
    const int m0   = blockIdx.x * BM;
    const int b    = blockIdx.x >> 4;           // 16 m-tiles per batch
    const int lane = tid & 63;
    const int w    = tid >> 6;
    const int wr   = w >> 1, wc = w & 1;
    const int fr   = lane & 15, quad = lane >> 4;

    // per-thread staging constants (row + swizzled source chunk per r-step)
    int mA[4], csA[4];
    #pragma unroll
    for (int r = 0; r < 4; ++r) {
        const int s = r * 256 + tid;
        mA[r]  = s >> 3;
        csA[r] = (s & 7) ^ (mA[r] & 7);
    }

    // stage A(128x64) + B(128x64) bf16 tile pair for flat iter it=(nn,kt)
    auto stage = [&](int bufsel, int it) {
        u16* Ab = (u16*)(smem + bufsel * 32768);
        u16* Bb = Ab + 8192;
        const int nn = it >> 3, kt = it & 7;
        const size_t aoff = (size_t)kt * 64;
        const size_t boff = (size_t)nn * (128 * 512) + (size_t)kt * 64;
        #pragma unroll
        for (int r = 0; r < 4; ++r) {
            async_cp16(Ab + (r * 256 + (tid & 192)) * 8,
                       encb + (size_t)(m0 + mA[r]) * 512 + aoff + csA[r] * 8);
            async_cp16(Bb + (r * 256 + (tid & 192)) * 8,
                       wvT + (size_t)mA[r] * 512 + boff + csA[r] * 8);
        }
    };

    floatx4 acc2[2] = {};
    int cur = 0;

    stage(0, 0);
    __syncthreads();

    for (int nn = 0; nn < 8; ++nn) {
        const int n0 = nn * 128;

        // per-slice operand prefetch (L1/L2-resident; hidden under kt loop)
        float qv[4];
        #pragma unroll
        for (int nt = 0; nt < 4; ++nt) {
            const int col = n0 + wc * 64 + nt * 16 + fr;
            qv[nt] = query_ws[(size_t)b * IHD + col] + bv[col];
        }
        bf16x8 wfr[4];
        #pragma unroll
        for (int ks = 0; ks < 4; ++ks)
            #pragma unroll
            for (int j = 0; j < 8; ++j)
                wfr[ks][j] = *(const __bf16*)&wfb[(n0 + ks * 32 + quad * 8 + j) * 8 + fr];

        floatx4 acc[4][4] = {};

        for (int kt = 0; kt < 8; ++kt) {
            // issue next tile's loads BEFORE computing current tile
            const int itn = nn * 8 + kt + 1;
            if (itn < 64) stage(cur ^ 1, itn);

            u16* Ab = (u16*)(smem + cur * 32768);
            u16* Bb = Ab + 8192;
            #pragma unroll
            for (int s2 = 0; s2 < 2; ++s2) {
                bf16x8 af[4], bfr[4];
                #pragma unroll
                for (int mt = 0; mt < 4; ++mt) {
                    const int ma = wr * 64 + mt * 16 + fr;
                    const int ca = (s2 * 4 + quad) ^ (ma & 7);
                    af[mt] = *(const bf16x8*)&Ab[ma * 64 + ca * 8];
                }
                #pragma unroll
                for (int nt = 0; nt < 4; ++nt) {
                    const int nb = wc * 64 + nt * 16 + fr;
                    const int cb = (s2 * 4 + quad) ^ (nb & 7);
                    bfr[nt] = *(const bf16x8*)&Bb[nb * 64 + cb * 8];
                }
                #pragma unroll
                for (int mt = 0; mt < 4; ++mt)
                    #pragma unroll
                    for (int nt = 0; nt < 4; ++nt)
                        acc[mt][nt] = __builtin_amdgcn_mfma_f32_16x16x32_bf16(
                            af[mt], bfr[nt], acc[mt][nt], 0, 0, 0);
            }
            __syncthreads();   // drains this iter's prefetch (issued ~350cy ago)
            cur ^= 1;
        }

        // ---- epilogue A: t = tanh(value + query + bv) -> tT (bf16)
        // tT aliases the just-consumed buffer (cur^1). XOR swizzle keeps
        // stride-128 rows conflict-free (<=2-way on write and read).
        u16* tT = (u16*)(smem + (cur ^ 1) * 32768);
        #pragma unroll
        for (int mt = 0; mt < 4; ++mt) {
            #pragma unroll
            for (int nt = 0; nt < 4; ++nt) {
                const int col = wc * 64 + nt * 16 + fr;
                #pragma unroll
                for (int reg = 0; reg < 4; ++reg) {
                    const int row = wr * 64 + mt * 16 + quad * 4 + reg;
                    ((__bf16*)tT)[row * 128 + (col ^ ((row & 7) << 3))] =
                        (__bf16)tanh_fast(acc[mt][nt][reg] + qv[nt]);
                }
            }
        }
        __syncthreads();

        // ---- epilogue B: stage-2 MFMA  P += t(128x128) @ Wf_slice(128x8)
        #pragma unroll
        for (int t = 0; t < 2; ++t) {
            const int row = w * 32 + t * 16 + fr;
            #pragma unroll
            for (int ks = 0; ks < 4; ++ks) {
                const bf16x8 ta = *(const bf16x8*)
                    &tT[row * 128 + ((ks * 32 + quad * 8) ^ ((row & 7) << 3))];
                acc2[t] = __builtin_amdgcn_mfma_f32_16x16x32_bf16(ta, wfr[ks], acc2[t], 0, 0, 0);
            }
        }
        __syncthreads();   // protect tT region before next slice stages into it
    }

    // ---- score: softplus(P + bf) * mask * exp(-beta*(kappa-u)^2)
    if (fr < NHEADS) {
        const float bfh = bf_g[fr];
        const float bet = beta_ws[b * NHEADS + fr];
        const float kap = kappa_out[b * NHEADS + fr];
        #pragma unroll
        for (int t = 0; t < 2; ++t) {
            #pragma unroll
            for (int reg = 0; reg < 4; ++reg) {
                const int row = m0 + w * 32 + t * 16 + quad * 4 + reg;
                const int s = row & 2047;
                const float alpha = softplus_f(acc2[t][reg] + bfh) * mask[row];
                const float du = kap - (float)s;
                score_out[(size_t)row * NHEADS + fr] = alpha * __expf(-bet * du * du);
            }
        }
    }
}

// ---------------------------------------------------------------------------
// context partials: part[sc][b][h][e] = sum_{s in chunk} score[b,s,h]*enc[b,s,e]
// grid (b=32, sc=16). Wave w owns heads {2w,2w+1} x all 512 e. No atomics.
// ---------------------------------------------------------------------------
__global__ __launch_bounds__(256) void context_kernel(
    const u16* __restrict__ encb, const float* __restrict__ score,
    float* __restrict__ ctx_part)
{
    __shared__ float s_sc[128 * NHEADS];
    const int b = blockIdx.x, sc = blockIdx.y, tid = threadIdx.x;
    const int lane = tid & 63, w = tid >> 6;
    const int e8 = lane * 8;
    const size_t srow0 = (size_t)b * SEQL + sc * 128;

    for (int i = tid; i < 128 * NHEADS; i += 256)
        s_sc[i] = score[srow0 * NHEADS + i];
    __syncthreads();

    float acc0[8] = {}, acc1[8] = {};
    const u16* ep = encb + srow0 * ENCD + e8;
    #pragma unroll 4
    for (int s = 0; s < 128; ++s) {
        const u16x8 ev = *(const u16x8*)(ep + (size_t)s * ENCD);
        const float2 sc2 = *(const float2*)&s_sc[s * NHEADS + 2 * w];
        #pragma unroll
        for (int j = 0; j < 8; ++j) {
            const float e = bf2f(ev[j]);
            acc0[j] = fmaf(sc2.x, e, acc0[j]);
            acc1[j] = fmaf(sc2.y, e, acc1[j]);
        }
    }

    float* outp = ctx_part + ((size_t)sc * BSZ + b) * (NHEADS * ENCD);
    *(float4*)&outp[(2 * w + 0) * ENCD + e8]     = make_float4(acc0[0], acc0[1], acc0[2], acc0[3]);
    *(float4*)&outp[(2 * w + 0) * ENCD + e8 + 4] = make_float4(acc0[4], acc0[5], acc0[6], acc0[7]);
    *(float4*)&outp[(2 * w + 1) * ENCD + e8]     = make_float4(acc1[0], acc1[1], acc1[2], acc1[3]);
    *(float4*)&outp[(2 * w + 1) * ENCD + e8 + 4] = make_float4(acc1[4], acc1[5], acc1[6], acc1[7]);
}

// ---------------------------------------------------------------------------
// ctx_ws[i] = sum_sc part[sc][i]   (i < 131072)
// ---------------------------------------------------------------------------
__global__ __launch_bounds__(256) void ctx_reduce_kernel(
    const float* __restrict__ part, float* __restrict__ ctx_ws)
{
    const int i = blockIdx.x * 256 + threadIdx.x;
    float a = 0.f;
    #pragma unroll
    for (int sc = 0; sc < 16; ++sc)
        a += part[(size_t)sc * 131072 + i];
    ctx_ws[i] = a;
}

// ---------------------------------------------------------------------------
// out_ctx[b,j] = ctx[b,:] @ Wfc[:,j] + bfc[j]
// ---------------------------------------------------------------------------
__global__ __launch_bounds__(256) void final_kernel(
    const float* __restrict__ ctx_ws, const float* __restrict__ Wfc,
    const float* __restrict__ bfc, float* __restrict__ out_ctx)
{
    __shared__ float s_ctx[32][128];
    const int jc = blockIdx.x, ks = blockIdx.y, tid = threadIdx.x;
    const int jl = tid & 31, bg = tid >> 5;
    const int j = jc * 32 + jl;
    float a0 = 0.f, a1 = 0.f, a2 = 0.f, a3 = 0.f;

    for (int t = 0; t < 4; ++t) {
        const int k0 = ks * 512 + t * 128;
        __syncthreads();
        for (int i = tid; i < 32 * 128; i += 256) {
            const int bb2 = i >> 7, kk = i & 127;
            s_ctx[bb2][kk] = ctx_ws[(size_t)bb2 * (NHEADS * ENCD) + k0 + kk];
        }
        __syncthreads();
        for (int kk = 0; kk < 128; ++kk) {
            const float wv = Wfc[(size_t)(k0 + kk) * ENCD + j];
            a0 = fmaf(s_ctx[bg * 4 + 0][kk], wv, a0);
            a1 = fmaf(s_ctx[bg * 4 + 1][kk], wv, a1);
            a2 = fmaf(s_ctx[bg * 4 + 2][kk], wv, a2);
            a3 = fmaf(s_ctx[bg * 4 + 3][kk], wv, a3);
        }
    }
    const float bias = (ks == 0) ? bfc[j] : 0.0f;
    atomicAdd(&out_ctx[(bg * 4 + 0) * ENCD + j], a0 + bias);
    atomicAdd(&out_ctx[(bg * 4 + 1) * ENCD + j], a1 + bias);
    atomicAdd(&out_ctx[(bg * 4 + 2) * ENCD + j], a2 + bias);
    atomicAdd(&out_ctx[(bg * 4 + 3) * ENCD + j], a3 + bias);
}

// ---------------------------------------------------------------------------
extern "C" void kernel_launch(void* const* d_in, const int* in_sizes, int n_in,
                              void* d_out, int out_size, void* d_ws, size_t ws_size,
                              hipStream_t stream)
{
    const float* enc   = (const float*)d_in[0];
    const float* dec   = (const float*)d_in[1];
    const float* kapin = (const float*)d_in[2];
    const float* mask  = (const float*)d_in[3];
    const float* Wv    = (const float*)d_in[4];
    const float* bv    = (const float*)d_in[5];
    const float* Wq    = (const float*)d_in[6];
    const float* bq    = (const float*)d_in[7];
    const float* Wf    = (const float*)d_in[8];
    const float* bf    = (const float*)d_in[9];
    const float* Wb    = (const float*)d_in[10];
    const float* bb    = (const float*)d_in[11];
    const float* Wk    = (const float*)d_in[12];
    const float* bk    = (const float*)d_in[13];
    const float* Wfc   = (const float*)d_in[14];
    const float* bfc   = (const float*)d_in[15];

    // outputs: context(32*512) | kappa(32*8) | score(32*2048*8)
    float* out       = (float*)d_out;
    float* out_ctx   = out;
    float* out_kappa = out + 16384;
    float* out_score = out + 16640;

    // workspace layout (bytes)
    char* w = (char*)d_ws;
    u16*   enc_bf   = (u16*)w;                     // 67108864 B
    float* ctx_part = (float*)(w + 67108864);      //  8388608 B
    u16*   wvT      = (u16*)(w + 75497472);        //  1048576 B
    float* q_ws     = (float*)(w + 76546048);      //   131072 B
    float* beta_ws  = (float*)(w + 76677120);      //     1024 B
    float* ctx_ws   = (float*)(w + 76678144);      //   524288 B
    u16*   wfb      = (u16*)(w + 77202432);        //    16400 B
                                                   // total 77218832 B

    hipMemsetAsync(out_ctx, 0, 16384 * sizeof(float), stream);

    conv_enc_kernel<<<dim3(16384), dim3(256), 0, stream>>>(enc, enc_bf);
    conv_w_kernel<<<dim3(129), dim3(256), 0, stream>>>(Wv, Wf, wvT, wfb);

    prep_kernel<<<dim3(BSZ, 33), dim3(256), 0, stream>>>(
        dec, kapin, Wq, bq, Wb, bb, Wk, bk, q_ws, beta_ws, out_kappa);

    gemm_score_kernel<<<dim3((BSZ * SEQL) / BM), dim3(256), 0, stream>>>(
        enc_bf, wvT, bv, wfb, bf, mask, q_ws, beta_ws, out_kappa, out_score);

    context_kernel<<<dim3(BSZ, 16), dim3(256), 0, stream>>>(
        enc_bf, out_score, ctx_part);

    ctx_reduce_kernel<<<dim3(512), dim3(256), 0, stream>>>(ctx_part, ctx_ws);

    final_kernel<<<dim3(16, 8), dim3(256), 0, stream>>>(
        ctx_ws, Wfc, bfc, out_ctx);
}

// Round 2
// 437.110 us; speedup vs baseline: 1.1335x; 1.1335x over previous
//
#include <hip/hip_runtime.h>
#include <cstdint>
#include <cstddef>

#define BSZ    32
#define SEQL   2048
#define ENCD   512
#define DE     1024   // DEC + ENC
#define NHEADS 8
#define IHD    1024   // INTERM * HEADS

typedef unsigned short u16;
typedef __bf16 bf16x8 __attribute__((ext_vector_type(8)));
typedef float floatx4 __attribute__((ext_vector_type(4)));
typedef unsigned short u16x8 __attribute__((ext_vector_type(8)));

__device__ __forceinline__ u16 f2bf(float f) {
    unsigned int u = __float_as_uint(f);
    u = (u + 0x7FFFu + ((u >> 16) & 1u)) >> 16;   // RNE
    return (u16)u;
}
__device__ __forceinline__ float bf2f(u16 v) {
    return __uint_as_float(((unsigned int)v) << 16);
}
__device__ __forceinline__ float softplus_f(float x) {
    return fmaxf(x, 0.0f) + log1pf(__expf(-fabsf(x)));
}
__device__ __forceinline__ float tanh_fast(float x) {
    const float e = __expf(2.0f * x);
    return 1.0f - 2.0f / (e + 1.0f);
}
__device__ __forceinline__ void async_cp16(u16* lds, const u16* g) {
    __builtin_amdgcn_global_load_lds(
        (const __attribute__((address_space(1))) unsigned int*)g,
        (__attribute__((address_space(3))) unsigned int*)lds, 16, 0, 0);
}

// ---------------------------------------------------------------------------
// fp32 -> bf16 enc conversion (feeds gemm and context kernels)
// ---------------------------------------------------------------------------
__global__ __launch_bounds__(256) void conv_enc_kernel(const float* __restrict__ in,
                                                       u16* __restrict__ out) {
    const size_t i = (size_t)blockIdx.x * 256 + threadIdx.x;   // group of 8
    const float4* p = (const float4*)in + i * 2;
    const float4 a = p[0], b = p[1];
    u16x8 o;
    o[0] = f2bf(a.x); o[1] = f2bf(a.y); o[2] = f2bf(a.z); o[3] = f2bf(a.w);
    o[4] = f2bf(b.x); o[5] = f2bf(b.y); o[6] = f2bf(b.z); o[7] = f2bf(b.w);
    *((u16x8*)out + i) = o;
}

// ---------------------------------------------------------------------------
// bid<128: WvT[n][k] = bf16(Wv[k][n]) 64x64 LDS tile transpose
// bid==128: Wf -> bf16 packed in MFMA B-fragment order:
//   wfb2[((nn*4+ks)*4+quad)*64 + fr8*8 + j] = Wf[nn*128+ks*32+quad*8+j][fr8]
//   so gemm reads one contiguous bf16x8 per (nn,ks) instead of 8 scalar gathers.
// ---------------------------------------------------------------------------
__global__ __launch_bounds__(256) void conv_w_kernel(const float* __restrict__ Wv,
                                                     const float* __restrict__ Wf,
                                                     u16* __restrict__ WvT,
                                                     u16* __restrict__ wfb) {
    __shared__ float tile[64 * 65];
    const int bid = blockIdx.x, tid = threadIdx.x;
    if (bid == 128) {
        for (int i = tid; i < 8192; i += 256) {
            const int j   = i & 7;
            const int fr8 = (i >> 3) & 7;
            const int qd  = (i >> 6) & 3;
            const int ks  = (i >> 8) & 3;
            const int nn  = i >> 10;
            const int row = nn * 128 + ks * 32 + qd * 8 + j;
            wfb[i] = f2bf(Wf[row * NHEADS + fr8]);
        }
        return;
    }
    const int nt = bid & 15, kt = bid >> 4;
    for (int i = tid; i < 4096; i += 256) {
        const int kk = i >> 6, nn = i & 63;
        tile[kk * 65 + nn] = Wv[(size_t)(kt * 64 + kk) * IHD + nt * 64 + nn];
    }
    __syncthreads();
    for (int i = tid; i < 4096; i += 256) {
        const int nn = i >> 6, kk = i & 63;
        WvT[(size_t)(nt * 64 + nn) * 512 + kt * 64 + kk] = f2bf(tile[kk * 65 + nn]);
    }
}

// ---------------------------------------------------------------------------
// prep: grid (BSZ, 33). y<32: 32 query cols, 8-way k-split + LDS reduce.
//       query_ws = dec@Wq + bq + bv  (bv folded here, saves gemm gathers)
//       y==32: beta = sp(dec@Wb+bb); kappa += sp(dec@Wk+bk)
// ---------------------------------------------------------------------------
__global__ __launch_bounds__(256) void prep_kernel(
    const float* __restrict__ dec, const float* __restrict__ kappa_in,
    const float* __restrict__ Wq, const float* __restrict__ bq,
    const float* __restrict__ bv,
    const float* __restrict__ Wb, const float* __restrict__ bb,
    const float* __restrict__ Wk, const float* __restrict__ bk,
    float* __restrict__ query_ws, float* __restrict__ beta_ws,
    float* __restrict__ kappa_out)
{
    __shared__ float s_dec[DE];
    __shared__ float s_red[256];
    const int b = blockIdx.x, y = blockIdx.y, tid = threadIdx.x;
    for (int i = tid; i < DE; i += 256) s_dec[i] = dec[b * DE + i];
    __syncthreads();

    if (y < 32) {
        const int cl = tid & 31, kg = tid >> 5;
        const int col = y * 32 + cl;
        float a = 0.f;
        const float* w = Wq + col;
        #pragma unroll 4
        for (int k = kg * 128; k < kg * 128 + 128; ++k)
            a = fmaf(s_dec[k], w[(size_t)k * IHD], a);
        s_red[tid] = a;
        __syncthreads();
        if (tid < 32) {
            float s = 0.f;
            #pragma unroll
            for (int i = 0; i < 8; ++i) s += s_red[i * 32 + tid];
            query_ws[(size_t)b * IHD + col] = s + bq[col] + bv[col];
        }
    } else {
        const int h = tid & 7, kg = tid >> 3;   // 32 k-groups of 32
        float ab = 0.f, ak = 0.f;
        for (int k = kg * 32; k < kg * 32 + 32; ++k) {
            const float d = s_dec[k];
            ab = fmaf(d, Wb[k * NHEADS + h], ab);
            ak = fmaf(d, Wk[k * NHEADS + h], ak);
        }
        s_red[tid] = ab;
        __syncthreads();
        for (int off = 128; off >= 8; off >>= 1) {
            if (tid < off) s_red[tid] += s_red[tid + off];
            __syncthreads();
        }
        const float abT = (tid < 8) ? s_red[tid] : 0.f;
        __syncthreads();
        s_red[tid] = ak;
        __syncthreads();
        for (int off = 128; off >= 8; off >>= 1) {
            if (tid < off) s_red[tid] += s_red[tid + off];
            __syncthreads();
        }
        if (tid < 8) {
            beta_ws[b * NHEADS + tid]   = softplus_f(bb[tid] + abT);
            kappa_out[b * NHEADS + tid] = kappa_in[b * NHEADS + tid]
                                        + softplus_f(bk[tid] + s_red[tid]);
        }
    }
}

// ---------------------------------------------------------------------------
// Main fused kernel. BM=128 -> 512 blocks (2/CU exact, no tail), LDS 64 KB.
// T3/T4 sync: raw s_barrier + counted vmcnt so prefetched global_load_lds
// stay in flight ACROSS barriers (never drain to 0 in the main loop).
// Per kt: stage(it+1) -> vmcnt(8) [tile it landed] -> barrierA -> 32 MFMA
// (setprio 1) -> barrierB. Tile it+1's 8 loads ride through both barriers.
// tT (128x128 bf16, XOR-swizzled) aliases buf1 (last kt tile is always odd).
// ---------------------------------------------------------------------------
#define BM 128
#define BN 128
#define BK 64

__global__ __launch_bounds__(256, 2) void gemm_score_kernel(
    const u16* __restrict__ encb, const u16* __restrict__ wvT,
    const u16* __restrict__ wfb2, const float* __restrict__ bf_g,
    const float* __restrict__ mask, const float* __restrict__ query_ws,
    const float* __restrict__ beta_ws, const float* __restrict__ kappa_out,
    float* __restrict__ score_out)
{
    // smem: buf0 [A 16KB | B 16KB] | buf1 [A 16KB | B 16KB]  = 64 KB
    __shared__ __align__(16) unsigned char smem[65536];

    const int tid  = threadIdx.x;
    const int m0   = blockIdx.x * BM;
    const int b    = blockIdx.x >> 4;           // 16 m-tiles per batch
    const int lane = tid & 63;
    const int w    = tid >> 6;
    const int wr   = w >> 1, wc = w & 1;
    const int fr   = lane & 15, quad = lane >> 4;

    // per-thread staging constants (row + swizzled source chunk per r-step)
    int mA[4], csA[4];
    #pragma unroll
    for (int r = 0; r < 4; ++r) {
        const int s = r * 256 + tid;
        mA[r]  = s >> 3;
        csA[r] = (s & 7) ^ (mA[r] & 7);
    }

    // stage A(128x64) + B(128x64) bf16 tile pair for flat iter it=(nn,kt):
    // 8 global_load_lds per thread (counts 8 on this wave's vmcnt)
    auto stage = [&](int bufsel, int it) {
        u16* Ab = (u16*)(smem + bufsel * 32768);
        u16* Bb = Ab + 8192;
        const int nn2 = it >> 3, kt2 = it & 7;
        const size_t aoff = (size_t)kt2 * 64;
        const size_t boff = (size_t)nn2 * (128 * 512) + (size_t)kt2 * 64;
        #pragma unroll
        for (int r = 0; r < 4; ++r) {
            async_cp16(Ab + (r * 256 + (tid & 192)) * 8,
                       encb + (size_t)(m0 + mA[r]) * 512 + aoff + csA[r] * 8);
            async_cp16(Bb + (r * 256 + (tid & 192)) * 8,
                       wvT + (size_t)mA[r] * 512 + boff + csA[r] * 8);
        }
    };

    floatx4 acc2[2] = {};

    stage(0, 0);

    for (int nn = 0; nn < 8; ++nn) {
        const int n0 = nn * 128;
        float qv[4];
        bf16x8 wfr[4];
        floatx4 acc[4][4] = {};

        #pragma unroll
        for (int kt = 0; kt < 8; ++kt) {
            const int it = nn * 8 + kt;
            // stage next tile into the other buffer (safe: barrierB of it-1
            // guaranteed all waves finished reading it)
            if (kt < 7) {
                stage((it + 1) & 1, it + 1);
            } else if (nn < 7) {
                stage((it + 1) & 1, it + 1);
            }
            if (kt == 0) {
                // epilogue operands for this n-slice; issued AFTER stage so
                // they are the 8 newest vm-ops (ride through vmcnt(16))
                #pragma unroll
                for (int nt = 0; nt < 4; ++nt)
                    qv[nt] = query_ws[(size_t)b * IHD + n0 + wc * 64 + nt * 16 + fr];
                #pragma unroll
                for (int ks = 0; ks < 4; ++ks)
                    wfr[ks] = *(const bf16x8*)&wfb2[((nn * 4 + ks) * 4 + quad) * 64
                                                    + (fr & 7) * 8];
            }
            // counted wait: only tile it must have landed.
            // kt==0: outstanding = tile it(8) + tile it+1(8) + qv/wfr(8) -> 16
            // kt>=1: outstanding = [qv/wfr] + tile it(8) + tile it+1(8) -> 8
            // last tile (nn==7,kt==7): nothing newer in flight -> 0
            if (kt == 7 && nn == 7) {
                asm volatile("s_waitcnt vmcnt(0)" ::: "memory");
            } else if (kt == 0) {
                asm volatile("s_waitcnt vmcnt(16)" ::: "memory");
            } else {
                asm volatile("s_waitcnt vmcnt(8)" ::: "memory");
            }
            __builtin_amdgcn_sched_barrier(0);
            __builtin_amdgcn_s_barrier();          // A: tile it landed (all waves)

            u16* Ab = (u16*)(smem + (it & 1) * 32768);
            u16* Bb = Ab + 8192;
            __builtin_amdgcn_s_setprio(1);
            #pragma unroll
            for (int s2 = 0; s2 < 2; ++s2) {
                bf16x8 af[4], bfr[4];
                #pragma unroll
                for (int mt = 0; mt < 4; ++mt) {
                    const int ma = wr * 64 + mt * 16 + fr;
                    const int ca = (s2 * 4 + quad) ^ (ma & 7);
                    af[mt] = *(const bf16x8*)&Ab[ma * 64 + ca * 8];
                }
                #pragma unroll
                for (int nt = 0; nt < 4; ++nt) {
                    const int nb = wc * 64 + nt * 16 + fr;
                    const int cb = (s2 * 4 + quad) ^ (nb & 7);
                    bfr[nt] = *(const bf16x8*)&Bb[nb * 64 + cb * 8];
                }
                #pragma unroll
                for (int mt = 0; mt < 4; ++mt)
                    #pragma unroll
                    for (int nt = 0; nt < 4; ++nt)
                        acc[mt][nt] = __builtin_amdgcn_mfma_f32_16x16x32_bf16(
                            af[mt], bfr[nt], acc[mt][nt], 0, 0, 0);
            }
            __builtin_amdgcn_s_setprio(0);
            __builtin_amdgcn_sched_barrier(0);
            __builtin_amdgcn_s_barrier();          // B: all done reading buf[it&1]
        }

        // ---- epilogue A: t = tanh(value + query) -> tT (bf16)
        // tT aliases buf1 (the buffer just consumed at kt=7; next-nn prefetch
        // is in buf0). XOR swizzle keeps stride-128 rows <=2-way on both sides.
        u16* tT = (u16*)(smem + 32768);
        #pragma unroll
        for (int mt = 0; mt < 4; ++mt) {
            #pragma unroll
            for (int nt = 0; nt < 4; ++nt) {
                const int col = wc * 64 + nt * 16 + fr;
                #pragma unroll
                for (int reg = 0; reg < 4; ++reg) {
                    const int row = wr * 64 + mt * 16 + quad * 4 + reg;
                    ((__bf16*)tT)[row * 128 + (col ^ ((row & 7) << 3))] =
                        (__bf16)tanh_fast(acc[mt][nt][reg] + qv[nt]);
                }
            }
        }
        asm volatile("s_waitcnt lgkmcnt(0)" ::: "memory");
        __builtin_amdgcn_sched_barrier(0);
        __builtin_amdgcn_s_barrier();              // C: tT visible to all waves

        // ---- epilogue B: stage-2 MFMA  P += t(128x128) @ Wf_slice(128x8)
        #pragma unroll
        for (int t = 0; t < 2; ++t) {
            const int row = w * 32 + t * 16 + fr;
            #pragma unroll
            for (int ks = 0; ks < 4; ++ks) {
                const bf16x8 ta = *(const bf16x8*)
                    &tT[row * 128 + ((ks * 32 + quad * 8) ^ ((row & 7) << 3))];
                acc2[t] = __builtin_amdgcn_mfma_f32_16x16x32_bf16(ta, wfr[ks], acc2[t], 0, 0, 0);
            }
        }
        __builtin_amdgcn_sched_barrier(0);
        __builtin_amdgcn_s_barrier();              // D: tT reads done before next
                                                   //    nn stages into buf1
    }

    // ---- score: softplus(P + bf) * mask * exp(-beta*(kappa-u)^2)
    if (fr < NHEADS) {
        const float bfh = bf_g[fr];
        const float bet = beta_ws[b * NHEADS + fr];
        const float kap = kappa_out[b * NHEADS + fr];
        #pragma unroll
        for (int t = 0; t < 2; ++t) {
            #pragma unroll
            for (int reg = 0; reg < 4; ++reg) {
                const int row = m0 + w * 32 + t * 16 + quad * 4 + reg;
                const int s = row & 2047;
                const float alpha = softplus_f(acc2[t][reg] + bfh) * mask[row];
                const float du = kap - (float)s;
                score_out[(size_t)row * NHEADS + fr] = alpha * __expf(-bet * du * du);
            }
        }
    }
}

// ---------------------------------------------------------------------------
// context partials: part[sc][b][h][e] = sum_{s in chunk} score[b,s,h]*enc[b,s,e]
// grid (b=32, sc=16). Wave w owns heads {2w,2w+1} x all 512 e. No atomics.
// ---------------------------------------------------------------------------
__global__ __launch_bounds__(256) void context_kernel(
    const u16* __restrict__ encb, const float* __restrict__ score,
    float* __restrict__ ctx_part)
{
    __shared__ float s_sc[128 * NHEADS];
    const int b = blockIdx.x, sc = blockIdx.y, tid = threadIdx.x;
    const int lane = tid & 63, w = tid >> 6;
    const int e8 = lane * 8;
    const size_t srow0 = (size_t)b * SEQL + sc * 128;

    for (int i = tid; i < 128 * NHEADS; i += 256)
        s_sc[i] = score[srow0 * NHEADS + i];
    __syncthreads();

    float acc0[8] = {}, acc1[8] = {};
    const u16* ep = encb + srow0 * ENCD + e8;
    #pragma unroll 4
    for (int s = 0; s < 128; ++s) {
        const u16x8 ev = *(const u16x8*)(ep + (size_t)s * ENCD);
        const float2 sc2 = *(const float2*)&s_sc[s * NHEADS + 2 * w];
        #pragma unroll
        for (int j = 0; j < 8; ++j) {
            const float e = bf2f(ev[j]);
            acc0[j] = fmaf(sc2.x, e, acc0[j]);
            acc1[j] = fmaf(sc2.y, e, acc1[j]);
        }
    }

    float* outp = ctx_part + ((size_t)sc * BSZ + b) * (NHEADS * ENCD);
    *(float4*)&outp[(2 * w + 0) * ENCD + e8]     = make_float4(acc0[0], acc0[1], acc0[2], acc0[3]);
    *(float4*)&outp[(2 * w + 0) * ENCD + e8 + 4] = make_float4(acc0[4], acc0[5], acc0[6], acc0[7]);
    *(float4*)&outp[(2 * w + 1) * ENCD + e8]     = make_float4(acc1[0], acc1[1], acc1[2], acc1[3]);
    *(float4*)&outp[(2 * w + 1) * ENCD + e8 + 4] = make_float4(acc1[4], acc1[5], acc1[6], acc1[7]);
}

// ---------------------------------------------------------------------------
// ctx_ws[i] = sum_sc part[sc][i]   (i < 131072)
// ---------------------------------------------------------------------------
__global__ __launch_bounds__(256) void ctx_reduce_kernel(
    const float* __restrict__ part, float* __restrict__ ctx_ws)
{
    const int i = blockIdx.x * 256 + threadIdx.x;
    float a = 0.f;
    #pragma unroll
    for (int sc = 0; sc < 16; ++sc)
        a += part[(size_t)sc * 131072 + i];
    ctx_ws[i] = a;
}

// ---------------------------------------------------------------------------
// out_ctx[b,j] = ctx[b,:] @ Wfc[:,j] + bfc[j]
// ---------------------------------------------------------------------------
__global__ __launch_bounds__(256) void final_kernel(
    const float* __restrict__ ctx_ws, const float* __restrict__ Wfc,
    const float* __restrict__ bfc, float* __restrict__ out_ctx)
{
    __shared__ float s_ctx[32][128];
    const int jc = blockIdx.x, ks = blockIdx.y, tid = threadIdx.x;
    const int jl = tid & 31, bg = tid >> 5;
    const int j = jc * 32 + jl;
    float a0 = 0.f, a1 = 0.f, a2 = 0.f, a3 = 0.f;

    for (int t = 0; t < 4; ++t) {
        const int k0 = ks * 512 + t * 128;
        __syncthreads();
        for (int i = tid; i < 32 * 128; i += 256) {
            const int bb2 = i >> 7, kk = i & 127;
            s_ctx[bb2][kk] = ctx_ws[(size_t)bb2 * (NHEADS * ENCD) + k0 + kk];
        }
        __syncthreads();
        for (int kk = 0; kk < 128; ++kk) {
            const float wv = Wfc[(size_t)(k0 + kk) * ENCD + j];
            a0 = fmaf(s_ctx[bg * 4 + 0][kk], wv, a0);
            a1 = fmaf(s_ctx[bg * 4 + 1][kk], wv, a1);
            a2 = fmaf(s_ctx[bg * 4 + 2][kk], wv, a2);
            a3 = fmaf(s_ctx[bg * 4 + 3][kk], wv, a3);
        }
    }
    const float bias = (ks == 0) ? bfc[j] : 0.0f;
    atomicAdd(&out_ctx[(bg * 4 + 0) * ENCD + j], a0 + bias);
    atomicAdd(&out_ctx[(bg * 4 + 1) * ENCD + j], a1 + bias);
    atomicAdd(&out_ctx[(bg * 4 + 2) * ENCD + j], a2 + bias);
    atomicAdd(&out_ctx[(bg * 4 + 3) * ENCD + j], a3 + bias);
}

// ---------------------------------------------------------------------------
extern "C" void kernel_launch(void* const* d_in, const int* in_sizes, int n_in,
                              void* d_out, int out_size, void* d_ws, size_t ws_size,
                              hipStream_t stream)
{
    const float* enc   = (const float*)d_in[0];
    const float* dec   = (const float*)d_in[1];
    const float* kapin = (const float*)d_in[2];
    const float* mask  = (const float*)d_in[3];
    const float* Wv    = (const float*)d_in[4];
    const float* bv    = (const float*)d_in[5];
    const float* Wq    = (const float*)d_in[6];
    const float* bq    = (const float*)d_in[7];
    const float* Wf    = (const float*)d_in[8];
    const float* bf    = (const float*)d_in[9];
    const float* Wb    = (const float*)d_in[10];
    const float* bb    = (const float*)d_in[11];
    const float* Wk    = (const float*)d_in[12];
    const float* bk    = (const float*)d_in[13];
    const float* Wfc   = (const float*)d_in[14];
    const float* bfc   = (const float*)d_in[15];

    // outputs: context(32*512) | kappa(32*8) | score(32*2048*8)
    float* out       = (float*)d_out;
    float* out_ctx   = out;
    float* out_kappa = out + 16384;
    float* out_score = out + 16640;

    // workspace layout (bytes)
    char* w = (char*)d_ws;
    u16*   enc_bf   = (u16*)w;                     // 67108864 B
    float* ctx_part = (float*)(w + 67108864);      //  8388608 B
    u16*   wvT      = (u16*)(w + 75497472);        //  1048576 B
    float* q_ws     = (float*)(w + 76546048);      //   131072 B
    float* beta_ws  = (float*)(w + 76677120);      //     1024 B
    float* ctx_ws   = (float*)(w + 76678144);      //   524288 B
    u16*   wfb      = (u16*)(w + 77202432);        //    16400 B (16384 used)
                                                   // total 77218832 B

    hipMemsetAsync(out_ctx, 0, 16384 * sizeof(float), stream);

    conv_enc_kernel<<<dim3(16384), dim3(256), 0, stream>>>(enc, enc_bf);
    conv_w_kernel<<<dim3(129), dim3(256), 0, stream>>>(Wv, Wf, wvT, wfb);

    prep_kernel<<<dim3(BSZ, 33), dim3(256), 0, stream>>>(
        dec, kapin, Wq, bq, bv, Wb, bb, Wk, bk, q_ws, beta_ws, out_kappa);

    gemm_score_kernel<<<dim3((BSZ * SEQL) / BM), dim3(256), 0, stream>>>(
        enc_bf, wvT, wfb, bf, mask, q_ws, beta_ws, out_kappa, out_score);

    context_kernel<<<dim3(BSZ, 16), dim3(256), 0, stream>>>(
        enc_bf, out_score, ctx_part);

    ctx_reduce_kernel<<<dim3(512), dim3(256), 0, stream>>>(ctx_part, ctx_ws);

    final_kernel<<<dim3(16, 8), dim3(256), 0, stream>>>(
        ctx_ws, Wfc, bfc, out_ctx);
}